// Round 7
// baseline (696.772 us; speedup 1.0000x reference)
//
#include <hip/hip_runtime.h>

typedef short s16;
typedef s16 bf16x8 __attribute__((ext_vector_type(8)));   // 8 bf16 bit patterns = 4 VGPRs
typedef float f32x4 __attribute__((ext_vector_type(4)));
typedef unsigned int u32;
typedef unsigned short u16;

#define HST 72   // u16 elements per LDS h-row (144 B)

__device__ __forceinline__ float fast_tanh(float x) {
    // tanh(x) = 1 - 2/(e^{2x}+1); error ~ulp, far below bf16x3 split noise
    float e = __expf(2.0f * x);
    float r = __builtin_amdgcn_rcpf(e + 1.0f);
    return fmaf(-2.0f, r, 1.0f);
}

// round-to-nearest-even bf16 bits from fp32 (finite only)
__device__ __forceinline__ u16 bfbits(float f) {
    u32 u = __builtin_bit_cast(u32, f);
    return (u16)((u + 0x7fffu + ((u >> 16) & 1u)) >> 16);
}

// A-fragment loader: row i (neuron), 8 consecutive k starting at jb; hi/lo split.
// A layout (16x16x32): lane holds row m=l&15, k=(l>>4)*8+e (+32 per chunk).
__device__ __forceinline__ void load_wfrag(const float* W, int i, int jb, bf16x8& hi, bf16x8& lo) {
    const float* p = W + i * 64 + jb;
#pragma unroll
    for (int e = 0; e < 8; ++e) {
        float f = p[e];
        u16 hb = bfbits(f);
        float fh = __builtin_bit_cast(float, ((u32)hb) << 16);
        hi[e] = (s16)hb;
        lo[e] = (s16)bfbits(f - fh);
    }
}

// one 16x16 output tile, K=64 as 2 chunks, 3-product split: Wh*hh + Wh*hl + Wl*hh
__device__ __forceinline__ void mm3(f32x4 acc[2], const bf16x8 wh[2], const bf16x8 wl[2],
                                    const bf16x8 bh[2], const bf16x8 bl[2]) {
#pragma unroll
    for (int c = 0; c < 2; ++c)
        acc[c] = __builtin_amdgcn_mfma_f32_16x16x32_bf16(wh[c], bh[c], acc[c], 0, 0, 0);
#pragma unroll
    for (int c = 0; c < 2; ++c)
        acc[c] = __builtin_amdgcn_mfma_f32_16x16x32_bf16(wh[c], bl[c], acc[c], 0, 0, 0);
#pragma unroll
    for (int c = 0; c < 2; ++c)
        acc[c] = __builtin_amdgcn_mfma_f32_16x16x32_bf16(wl[c], bh[c], acc[c], 0, 0, 0);
}

// split 4 h values (4 consecutive neurons) into hi/lo bf16 and write 2x ds_write_b64
__device__ __forceinline__ void store_h(u16* hi_row, u16* lo_row, int nb, const float h[4]) {
    u16 hb[4], lb[4];
#pragma unroll
    for (int r = 0; r < 4; ++r) {
        hb[r] = bfbits(h[r]);
        float fh = __builtin_bit_cast(float, ((u32)hb[r]) << 16);
        lb[r] = bfbits(h[r] - fh);
    }
    uint2 hv, lv;
    hv.x = (u32)hb[0] | ((u32)hb[1] << 16);
    hv.y = (u32)hb[2] | ((u32)hb[3] << 16);
    lv.x = (u32)lb[0] | ((u32)lb[1] << 16);
    lv.y = (u32)lb[2] | ((u32)lb[3] << 16);
    *(uint2*)(hi_row + nb) = hv;
    *(uint2*)(lo_row + nb) = lv;
}

// B-fragment read: col n=batch=l&15 (row pointer), k=32c+8g+e — contiguous b128, no unpack
__device__ __forceinline__ void read_bfrag(const u16* hi_row, const u16* lo_row, int g,
                                           bf16x8 bh[2], bf16x8 bl[2]) {
#pragma unroll
    for (int c = 0; c < 2; ++c) {
        bh[c] = *(const bf16x8*)(hi_row + 32 * c + 8 * g);
        bl[c] = *(const bf16x8*)(lo_row + 32 * c + 8 * g);
    }
}

__global__ __launch_bounds__(256, 1)
void rnn3_fused(const float* __restrict__ x,
                const float* __restrict__ wih0, const float* __restrict__ whh0,
                const float* __restrict__ bih0, const float* __restrict__ bhh0,
                const float* __restrict__ wih1, const float* __restrict__ whh1,
                const float* __restrict__ bih1, const float* __restrict__ bhh1,
                const float* __restrict__ wih2, const float* __restrict__ whh2,
                const float* __restrict__ bih2, const float* __restrict__ bhh2,
                const float* __restrict__ w1, const float* __restrict__ bf1,
                const float* __restrict__ w2, const float* __restrict__ bf2,
                const float* __restrict__ w3, const float* __restrict__ bf3,
                float* __restrict__ out)
{
    // h state: [buf][hi/lo][layer][batch][neuron+pad], ping-pong on buf
    __shared__ __align__(16) u16 H[2][2][3][16][HST];
    __shared__ float hf[16][65];    // final h2 fp32
    __shared__ float a1s[16][33];   // head stage 1
    __shared__ float a2s[16][17];   // head stage 2

    const int tid = (int)threadIdx.x;
    const int l = tid & 63;
    const int wv = tid >> 6;        // wave 0..3 owns neurons wv*16..wv*16+15
    const int ml = l & 15;
    const int g = l >> 4;           // 0..3
    const int blk = (int)blockIdx.x;
    const int nb = wv * 16 + 4 * g; // this thread's 4 neurons: nb..nb+3

    // ---- zero both H buffers (this is also the required h(-1)=0 state) ----
    {
        u32* hz = (u32*)&H[0][0][0][0][0];
        const int nz = (int)(sizeof(H) / 4);
        for (int i = tid; i < nz; i += 256) hz[i] = 0;
    }

    // ---- weight A-fragments (one-time, registers) ----
    bf16x8 W0h[2], W0l[2], I1h[2], I1l[2], H1h[2], H1l[2], I2h[2], I2l[2], H2h[2], H2l[2];
    {
        int arow = wv * 16 + ml;    // neuron row for A-frag
#pragma unroll
        for (int c = 0; c < 2; ++c) {
            int jb = 32 * c + 8 * g;
            load_wfrag(whh0, arow, jb, W0h[c], W0l[c]);
            load_wfrag(wih1, arow, jb, I1h[c], I1l[c]);
            load_wfrag(whh1, arow, jb, H1h[c], H1l[c]);
            load_wfrag(wih2, arow, jb, I2h[c], I2l[c]);
            load_wfrag(whh2, arow, jb, H2h[c], H2l[c]);
        }
    }
    float w0r[4][4], b0[4], b1[4], b2[4];
#pragma unroll
    for (int r = 0; r < 4; ++r) {
        int n = nb + r;
#pragma unroll
        for (int j = 0; j < 4; ++j) w0r[r][j] = wih0[n * 4 + j];
        b0[r] = bih0[n] + bhh0[n];
        b1[r] = bih1[n] + bhh1[n];
        b2[r] = bih2[n] + bhh2[n];
    }

    // B-fragment caches (h0,h1,h2), zero initial state
    bf16x8 B0h[2], B0l[2], B1h[2], B1l[2], B2h[2], B2l[2];
#pragma unroll
    for (int c = 0; c < 2; ++c)
#pragma unroll
        for (int e = 0; e < 8; ++e) {
            B0h[c][e] = 0; B0l[c][e] = 0;
            B1h[c][e] = 0; B1l[c][e] = 0;
            B2h[c][e] = 0; B2l[c][e] = 0;
        }

    const float4* xv = (const float4*)x;
    const long xrow = (long)(blk * 16 + ml) * 512;   // this thread's batch row
    float4 xn = xv[xrow];                            // x(0) prefetch

    __syncthreads();   // H zero-init visible to all

    float h2v[4] = {0.f, 0.f, 0.f, 0.f};

    // ---- skewed pipeline: phase p computes L0@t=p, L1@t=p-1, L2@t=p-2 ----
    // All GEMMs in a phase depend only on previous-phase state -> ONE barrier.
    // Ping-pong H: phase p stores+reads buf (p&1); next phase writes the other,
    // so this phase's reads never race the next phase's stores.
#pragma unroll 1
    for (int p = 0; p < 514; ++p) {
        const int cur = p & 1;
        float4 xc = xn;
        xn = xv[xrow + ((p + 1) & 511)];             // wrap read harmless

        const bool do0 = (p < 512);
        const bool do1 = (p >= 1) && (p <= 512);
        const bool do2 = (p >= 2);

        f32x4 a0[2], a1[2], a2[2];
        a0[0] = (f32x4){b0[0], b0[1], b0[2], b0[3]}; a0[1] = (f32x4){0.f, 0.f, 0.f, 0.f};
        a1[0] = (f32x4){b1[0], b1[1], b1[2], b1[3]}; a1[1] = (f32x4){0.f, 0.f, 0.f, 0.f};
        a2[0] = (f32x4){b2[0], b2[1], b2[2], b2[3]}; a2[1] = (f32x4){0.f, 0.f, 0.f, 0.f};

        if (do0) mm3(a0, W0h, W0l, B0h, B0l);                 // Whh0 * h0(p-1)
        if (do1) { mm3(a1, I1h, I1l, B0h, B0l);               // Wih1 * h0(p-1)
                   mm3(a1, H1h, H1l, B1h, B1l); }             // Whh1 * h1(p-2)
        if (do2) { mm3(a2, I2h, I2l, B1h, B1l);               // Wih2 * h1(p-2)
                   mm3(a2, H2h, H2l, B2h, B2l); }             // Whh2 * h2(p-3)

        if (do0) {   // layer 0 finish: + x(p) part (K=4, VALU), tanh, store h0(p)
            float hL[4];
#pragma unroll
            for (int r = 0; r < 4; ++r) {
                float s = a0[0][r] + a0[1][r];
                s = fmaf(xc.x, w0r[r][0], s);
                s = fmaf(xc.y, w0r[r][1], s);
                s = fmaf(xc.z, w0r[r][2], s);
                s = fmaf(xc.w, w0r[r][3], s);
                hL[r] = fast_tanh(s);
            }
            store_h(&H[cur][0][0][ml][0], &H[cur][1][0][ml][0], nb, hL);
        }
        if (do1) {   // layer 1: tanh, store h1(p-1)
            float hL[4];
#pragma unroll
            for (int r = 0; r < 4; ++r) hL[r] = fast_tanh(a1[0][r] + a1[1][r]);
            store_h(&H[cur][0][1][ml][0], &H[cur][1][1][ml][0], nb, hL);
        }
        if (do2) {   // layer 2: tanh, store h2(p-2); last phase (p=513) leaves h2(511)
            float hL[4];
#pragma unroll
            for (int r = 0; r < 4; ++r) { hL[r] = fast_tanh(a2[0][r] + a2[1][r]); h2v[r] = hL[r]; }
            store_h(&H[cur][0][2][ml][0], &H[cur][1][2][ml][0], nb, hL);
        }

        __syncthreads();

        read_bfrag(&H[cur][0][0][ml][0], &H[cur][1][0][ml][0], g, B0h, B0l);  // h0(p)
        read_bfrag(&H[cur][0][1][ml][0], &H[cur][1][1][ml][0], g, B1h, B1l);  // h1(p-1)
        read_bfrag(&H[cur][0][2][ml][0], &H[cur][1][2][ml][0], g, B2h, B2l);  // h2(p-2)
    }

    // ---------- MLP head (fp32, one-time) ----------
#pragma unroll
    for (int r = 0; r < 4; ++r) hf[ml][nb + r] = h2v[r];
    __syncthreads();

    {   // stage 1: [16x64] @ w1^T -> relu -> [16x32]; 256 threads, 2 outputs each
        int r = tid & 15, o2 = tid >> 4;   // o2 0..15
#pragma unroll
        for (int k = 0; k < 2; ++k) {
            int o = o2 * 2 + k;
            float s = bf1[o];
            for (int j = 0; j < 64; ++j) s = fmaf(hf[r][j], w1[o * 64 + j], s);
            a1s[r][o] = fmaxf(s, 0.f);
        }
    }
    __syncthreads();
    {   // stage 2: [16x32] @ w2^T -> [16x16]; one output each
        int r = tid & 15, o = tid >> 4;
        float s = bf2[o];
        for (int j = 0; j < 32; ++j) s = fmaf(a1s[r][j], w2[o * 32 + j], s);
        a2s[r][o] = s;
    }
    __syncthreads();
    if (tid < 16) {   // stage 3: [16x16] @ w3^T -> [16]
        float s = bf3[0];
        for (int j = 0; j < 16; ++j) s = fmaf(a2s[tid][j], w3[j], s);
        out[blk * 16 + tid] = s;
    }
}

extern "C" void kernel_launch(void* const* d_in, const int* in_sizes, int n_in,
                              void* d_out, int out_size, void* d_ws, size_t ws_size,
                              hipStream_t stream) {
    const float* x    = (const float*)d_in[0];
    const float* wih0 = (const float*)d_in[1];
    const float* whh0 = (const float*)d_in[2];
    const float* bih0 = (const float*)d_in[3];
    const float* bhh0 = (const float*)d_in[4];
    const float* wih1 = (const float*)d_in[5];
    const float* whh1 = (const float*)d_in[6];
    const float* bih1 = (const float*)d_in[7];
    const float* bhh1 = (const float*)d_in[8];
    const float* wih2 = (const float*)d_in[9];
    const float* whh2 = (const float*)d_in[10];
    const float* bih2 = (const float*)d_in[11];
    const float* bhh2 = (const float*)d_in[12];
    const float* w1   = (const float*)d_in[13];
    const float* bf1  = (const float*)d_in[14];
    const float* w2   = (const float*)d_in[15];
    const float* bf2  = (const float*)d_in[16];
    const float* w3   = (const float*)d_in[17];
    const float* bf3  = (const float*)d_in[18];

    rnn3_fused<<<dim3(256), dim3(256), 0, stream>>>(
        x, wih0, whh0, bih0, bhh0, wih1, whh1, bih1, bhh1,
        wih2, whh2, bih2, bhh2, w1, bf1, w2, bf2, w3, bf3,
        (float*)d_out);
}

// Round 10
// 524.389 us; speedup vs baseline: 1.3287x; 1.3287x over previous
//
#include <hip/hip_runtime.h>

typedef short s16;
typedef s16 bf16x8 __attribute__((ext_vector_type(8)));   // 8 bf16 bit patterns = 4 VGPRs
typedef float f32x4 __attribute__((ext_vector_type(4)));
typedef unsigned int u32;
typedef unsigned short u16;

#define HST 72   // u16 elements per LDS h-row (144 B)

__device__ __forceinline__ float fast_tanh(float x) {
    // tanh(x) = 1 - 2/(e^{2x}+1); error ~ulp, far below bf16x3 split noise
    float e = __expf(2.0f * x);
    float r = __builtin_amdgcn_rcpf(e + 1.0f);
    return fmaf(-2.0f, r, 1.0f);
}

// round-to-nearest-even bf16 bits from fp32 (finite only)
__device__ __forceinline__ u16 bfbits(float f) {
    u32 u = __builtin_bit_cast(u32, f);
    return (u16)((u + 0x7fffu + ((u >> 16) & 1u)) >> 16);
}

// A-fragment loader: row i (neuron), 8 consecutive k starting at jb; hi/lo split.
// A layout (16x16x32): lane holds row m=l&15, k=(l>>4)*8+e (+32 per chunk).
__device__ __forceinline__ void load_wfrag(const float* W, int i, int jb, bf16x8& hi, bf16x8& lo) {
    const float* p = W + i * 64 + jb;
#pragma unroll
    for (int e = 0; e < 8; ++e) {
        float f = p[e];
        u16 hb = bfbits(f);
        float fh = __builtin_bit_cast(float, ((u32)hb) << 16);
        hi[e] = (s16)hb;
        lo[e] = (s16)bfbits(f - fh);
    }
}

// one 16x16 output tile, K=64 as 2 chunks, 3-product split: Wh*hh + Wh*hl + Wl*hh
__device__ __forceinline__ void mm3(f32x4 acc[2], const bf16x8 wh[2], const bf16x8 wl[2],
                                    const bf16x8 bh[2], const bf16x8 bl[2]) {
#pragma unroll
    for (int c = 0; c < 2; ++c)
        acc[c] = __builtin_amdgcn_mfma_f32_16x16x32_bf16(wh[c], bh[c], acc[c], 0, 0, 0);
#pragma unroll
    for (int c = 0; c < 2; ++c)
        acc[c] = __builtin_amdgcn_mfma_f32_16x16x32_bf16(wh[c], bl[c], acc[c], 0, 0, 0);
#pragma unroll
    for (int c = 0; c < 2; ++c)
        acc[c] = __builtin_amdgcn_mfma_f32_16x16x32_bf16(wl[c], bh[c], acc[c], 0, 0, 0);
}

// split 4 h values (4 consecutive neurons) into hi/lo bf16 and write 2x ds_write_b64
__device__ __forceinline__ void store_h(u16* hi_row, u16* lo_row, int nb, const float h[4]) {
    u16 hb[4], lb[4];
#pragma unroll
    for (int r = 0; r < 4; ++r) {
        hb[r] = bfbits(h[r]);
        float fh = __builtin_bit_cast(float, ((u32)hb[r]) << 16);
        lb[r] = bfbits(h[r] - fh);
    }
    uint2 hv, lv;
    hv.x = (u32)hb[0] | ((u32)hb[1] << 16);
    hv.y = (u32)hb[2] | ((u32)hb[3] << 16);
    lv.x = (u32)lb[0] | ((u32)lb[1] << 16);
    lv.y = (u32)lb[2] | ((u32)lb[3] << 16);
    *(uint2*)(hi_row + nb) = hv;
    *(uint2*)(lo_row + nb) = lv;
}

// B-fragment read: col n=batch=l&15 (row pointer), k=32c+8g+e — contiguous b128, no unpack
__device__ __forceinline__ void read_bfrag(const u16* hi_row, const u16* lo_row, int g,
                                           bf16x8 bh[2], bf16x8 bl[2]) {
#pragma unroll
    for (int c = 0; c < 2; ++c) {
        bh[c] = *(const bf16x8*)(hi_row + 32 * c + 8 * g);
        bl[c] = *(const bf16x8*)(lo_row + 32 * c + 8 * g);
    }
}

// 8 waves, skewed pipeline (phase p: L0@t=p, L1@t=p-1, L2@t=p-2), one barrier/phase.
// P waves (0-3): L0 tile i + L2 tile i.  Q waves (4-7): L1 tile i.
// Register-unified: F1 pairs with B0 (P: Whh0, Q: Wih1); F2 pairs with B1
// (P: Wih2, Q: Whh1); F3 pairs with B2 (P: Whh2, Q unused).
__global__ __launch_bounds__(512, 2)
void rnn3_fused(const float* __restrict__ x,
                const float* __restrict__ wih0, const float* __restrict__ whh0,
                const float* __restrict__ bih0, const float* __restrict__ bhh0,
                const float* __restrict__ wih1, const float* __restrict__ whh1,
                const float* __restrict__ bih1, const float* __restrict__ bhh1,
                const float* __restrict__ wih2, const float* __restrict__ whh2,
                const float* __restrict__ bih2, const float* __restrict__ bhh2,
                const float* __restrict__ w1, const float* __restrict__ bf1,
                const float* __restrict__ w2, const float* __restrict__ bf2,
                const float* __restrict__ w3, const float* __restrict__ bf3,
                float* __restrict__ out)
{
    // h state: [buf][hi/lo][layer][batch][neuron+pad], ping-pong on buf
    __shared__ __align__(16) u16 H[2][2][3][16][HST];
    __shared__ float hf[16][65];    // final h2 fp32
    __shared__ float a1s[16][33];   // head stage 1
    __shared__ float a2s[16][17];   // head stage 2

    const int tid = (int)threadIdx.x;
    const int l = tid & 63;
    const int wv = tid >> 6;        // 0..7
    const int i = wv & 3;           // neuron-tile index: neurons i*16..i*16+15
    const bool isP = wv < 4;
    const int ml = l & 15;
    const int g = l >> 4;           // 0..3
    const int blk = (int)blockIdx.x;
    const int nb = i * 16 + 4 * g;  // this thread's 4 neurons within its tile

    // ---- zero both H buffers (this is also the required h(-1)=0 state) ----
    {
        u32* hz = (u32*)&H[0][0][0][0][0];
        const int nz = (int)(sizeof(H) / 4);
        for (int k = tid; k < nz; k += 512) hz[k] = 0;
    }

    // ---- weight A-fragments (role-dependent, unified registers) ----
    const float* WF1 = isP ? whh0 : wih1;
    const float* WF2 = isP ? wih2 : whh1;
    const float* WF3 = isP ? whh2 : whh1;   // F3 unused by Q (dup load, harmless)
    bf16x8 F1h[2], F1l[2], F2h[2], F2l[2], F3h[2], F3l[2];
    {
        int arow = i * 16 + ml;
#pragma unroll
        for (int c = 0; c < 2; ++c) {
            int jb = 32 * c + 8 * g;
            load_wfrag(WF1, arow, jb, F1h[c], F1l[c]);
            load_wfrag(WF2, arow, jb, F2h[c], F2l[c]);
            load_wfrag(WF3, arow, jb, F3h[c], F3l[c]);
        }
    }
    float w0r[4][4], bU[4], bV[4];
#pragma unroll
    for (int r = 0; r < 4; ++r) {
        int n = nb + r;
#pragma unroll
        for (int j = 0; j < 4; ++j) w0r[r][j] = wih0[n * 4 + j];
        bU[r] = isP ? (bih0[n] + bhh0[n]) : (bih1[n] + bhh1[n]);
        bV[r] = bih2[n] + bhh2[n];
    }

    // B-fragment caches: B0=h0, B1=h1, B2=h2 (P only); zero initial state
    bf16x8 B0h[2], B0l[2], B1h[2], B1l[2], B2h[2], B2l[2];
#pragma unroll
    for (int c = 0; c < 2; ++c)
#pragma unroll
        for (int e = 0; e < 8; ++e) {
            B0h[c][e] = 0; B0l[c][e] = 0;
            B1h[c][e] = 0; B1l[c][e] = 0;
            B2h[c][e] = 0; B2l[c][e] = 0;
        }

    const float4* xv = (const float4*)x;
    const long xrow = (long)(blk * 16 + ml) * 512;   // P waves' batch row
    float4 xn;
    if (isP) xn = xv[xrow];                          // x(0) prefetch

    __syncthreads();   // H zero-init visible to all

    float h2v[4] = {0.f, 0.f, 0.f, 0.f};

#pragma unroll 1
    for (int p = 0; p < 514; ++p) {
        const int cur = p & 1;

        f32x4 aU[2], aV[2];
        aU[0] = (f32x4){bU[0], bU[1], bU[2], bU[3]}; aU[1] = (f32x4){0.f, 0.f, 0.f, 0.f};
        aV[0] = (f32x4){bV[0], bV[1], bV[2], bV[3]}; aV[1] = (f32x4){0.f, 0.f, 0.f, 0.f};

        if (isP) {
            float4 xc = xn;
            xn = xv[xrow + ((p + 1) & 511)];         // wrap read harmless
            const bool do0 = (p < 512);
            const bool do2 = (p >= 2);

            // all MFMAs first (independent chains), then VALU finishes
            if (do0) mm3(aU, F1h, F1l, B0h, B0l);           // Whh0 * h0(p-1)
            if (do2) { mm3(aV, F2h, F2l, B1h, B1l);         // Wih2 * h1(p-2)
                       mm3(aV, F3h, F3l, B2h, B2l); }       // Whh2 * h2(p-3)

            if (do0) {   // layer 0: + x(p) part (K=4, VALU), tanh, store h0(p)
                float hL[4];
#pragma unroll
                for (int r = 0; r < 4; ++r) {
                    float s = aU[0][r] + aU[1][r];
                    s = fmaf(xc.x, w0r[r][0], s);
                    s = fmaf(xc.y, w0r[r][1], s);
                    s = fmaf(xc.z, w0r[r][2], s);
                    s = fmaf(xc.w, w0r[r][3], s);
                    hL[r] = fast_tanh(s);
                }
                store_h(&H[cur][0][0][ml][0], &H[cur][1][0][ml][0], nb, hL);
            }
            if (do2) {   // layer 2: tanh, store h2(p-2); p=513 leaves h2(511)
                float hL[4];
#pragma unroll
                for (int r = 0; r < 4; ++r) { hL[r] = fast_tanh(aV[0][r] + aV[1][r]); h2v[r] = hL[r]; }
                store_h(&H[cur][0][2][ml][0], &H[cur][1][2][ml][0], nb, hL);
            }
        } else {
            const bool do1 = (p >= 1) && (p <= 512);
            if (do1) {   // layer 1: Wih1*h0(p-1) + Whh1*h1(p-2), tanh, store h1(p-1)
                mm3(aU, F1h, F1l, B0h, B0l);
                mm3(aU, F2h, F2l, B1h, B1l);
                float hL[4];
#pragma unroll
                for (int r = 0; r < 4; ++r) hL[r] = fast_tanh(aU[0][r] + aU[1][r]);
                store_h(&H[cur][0][1][ml][0], &H[cur][1][1][ml][0], nb, hL);
            }
        }

        __syncthreads();

        read_bfrag(&H[cur][0][0][ml][0], &H[cur][1][0][ml][0], g, B0h, B0l);  // h0
        read_bfrag(&H[cur][0][1][ml][0], &H[cur][1][1][ml][0], g, B1h, B1l);  // h1
        if (isP)
            read_bfrag(&H[cur][0][2][ml][0], &H[cur][1][2][ml][0], g, B2h, B2l);  // h2
    }

    // ---------- MLP head (fp32, one-time) ----------
    if (isP) {
#pragma unroll
        for (int r = 0; r < 4; ++r) hf[ml][nb + r] = h2v[r];
    }
    __syncthreads();

    {   // stage 1: [16x64] @ w1^T -> relu -> [16x32]; 512 threads, 1 output each
        int r = tid & 15, o = tid >> 4;   // o 0..31
        float s = bf1[o];
        for (int j = 0; j < 64; ++j) s = fmaf(hf[r][j], w1[o * 64 + j], s);
        a1s[r][o] = fmaxf(s, 0.f);
    }
    __syncthreads();
    if (tid < 256) {   // stage 2: [16x32] @ w2^T -> [16x16]; one output each
        int r = tid & 15, o = tid >> 4;
        float s = bf2[o];
        for (int j = 0; j < 32; ++j) s = fmaf(a1s[r][j], w2[o * 32 + j], s);
        a2s[r][o] = s;
    }
    __syncthreads();
    if (tid < 16) {   // stage 3: [16x16] @ w3^T -> [16]
        float s = bf3[0];
        for (int j = 0; j < 16; ++j) s = fmaf(a2s[tid][j], w3[j], s);
        out[blk * 16 + tid] = s;
    }
}

extern "C" void kernel_launch(void* const* d_in, const int* in_sizes, int n_in,
                              void* d_out, int out_size, void* d_ws, size_t ws_size,
                              hipStream_t stream) {
    const float* x    = (const float*)d_in[0];
    const float* wih0 = (const float*)d_in[1];
    const float* whh0 = (const float*)d_in[2];
    const float* bih0 = (const float*)d_in[3];
    const float* bhh0 = (const float*)d_in[4];
    const float* wih1 = (const float*)d_in[5];
    const float* whh1 = (const float*)d_in[6];
    const float* bih1 = (const float*)d_in[7];
    const float* bhh1 = (const float*)d_in[8];
    const float* wih2 = (const float*)d_in[9];
    const float* whh2 = (const float*)d_in[10];
    const float* bih2 = (const float*)d_in[11];
    const float* bhh2 = (const float*)d_in[12];
    const float* w1   = (const float*)d_in[13];
    const float* bf1  = (const float*)d_in[14];
    const float* w2   = (const float*)d_in[15];
    const float* bf2  = (const float*)d_in[16];
    const float* w3   = (const float*)d_in[17];
    const float* bf3  = (const float*)d_in[18];

    rnn3_fused<<<dim3(256), dim3(512), 0, stream>>>(
        x, wih0, whh0, bih0, bhh0, wih1, whh1, bih1, bhh1,
        wih2, whh2, bih2, bhh2, w1, bf1, w2, bf2, w3, bf3,
        (float*)d_out);
}

// Round 11
// 478.290 us; speedup vs baseline: 1.4568x; 1.0964x over previous
//
#include <hip/hip_runtime.h>

typedef short s16;
typedef s16 bf16x8 __attribute__((ext_vector_type(8)));   // 8 bf16 bit patterns = 4 VGPRs
typedef float f32x4 __attribute__((ext_vector_type(4)));
typedef unsigned int u32;
typedef unsigned short u16;

#define HST 72   // u16 elements per LDS h-row (144 B)

__device__ __forceinline__ float fast_tanh(float x) {
    // tanh(x) = 1 - 2/(2^(x*2/ln2)+1); ~ulp error, far below bf16x3 split noise
    float e = __builtin_amdgcn_exp2f(x * 2.885390081777927f);
    float r = __builtin_amdgcn_rcpf(e + 1.0f);
    return fmaf(-2.0f, r, 1.0f);
}

// round-to-nearest-even bf16 bits from fp32 (finite only) — init path only
__device__ __forceinline__ u16 bfbits(float f) {
    u32 u = __builtin_bit_cast(u32, f);
    return (u16)((u + 0x7fffu + ((u >> 16) & 1u)) >> 16);
}

// A-fragment loader: row i (neuron), 8 consecutive k starting at jb; hi/lo split.
__device__ __forceinline__ void load_wfrag(const float* W, int i, int jb, bf16x8& hi, bf16x8& lo) {
    const float* p = W + i * 64 + jb;
#pragma unroll
    for (int e = 0; e < 8; ++e) {
        float f = p[e];
        u16 hb = bfbits(f);
        float fh = __builtin_bit_cast(float, ((u32)hb) << 16);
        hi[e] = (s16)hb;
        lo[e] = (s16)bfbits(f - fh);
    }
}

// one 16x16 output tile, K=64 as 2 chunks, 3-product split: Wh*hh + Wh*hl + Wl*hh
__device__ __forceinline__ void mm3(f32x4 acc[2], const bf16x8 wh[2], const bf16x8 wl[2],
                                    const bf16x8 bh[2], const bf16x8 bl[2]) {
#pragma unroll
    for (int c = 0; c < 2; ++c)
        acc[c] = __builtin_amdgcn_mfma_f32_16x16x32_bf16(wh[c], bh[c], acc[c], 0, 0, 0);
#pragma unroll
    for (int c = 0; c < 2; ++c)
        acc[c] = __builtin_amdgcn_mfma_f32_16x16x32_bf16(wh[c], bl[c], acc[c], 0, 0, 0);
#pragma unroll
    for (int c = 0; c < 2; ++c)
        acc[c] = __builtin_amdgcn_mfma_f32_16x16x32_bf16(wl[c], bh[c], acc[c], 0, 0, 0);
}

// split 4 h values into hi/lo bf16 via v_cvt_pk_bf16_f32 (RNE) — 12 ops vs ~40
__device__ __forceinline__ void store_h(u16* hi_row, u16* lo_row, int nb, const float h[4]) {
    u32 hx, hy, lx, ly;
    asm("v_cvt_pk_bf16_f32 %0, %1, %2" : "=v"(hx) : "v"(h[0]), "v"(h[1]));
    asm("v_cvt_pk_bf16_f32 %0, %1, %2" : "=v"(hy) : "v"(h[2]), "v"(h[3]));
    float f0 = __builtin_bit_cast(float, hx << 16);
    float f1 = __builtin_bit_cast(float, hx & 0xffff0000u);
    float f2 = __builtin_bit_cast(float, hy << 16);
    float f3 = __builtin_bit_cast(float, hy & 0xffff0000u);
    float l0 = h[0] - f0, l1 = h[1] - f1, l2 = h[2] - f2, l3 = h[3] - f3;
    asm("v_cvt_pk_bf16_f32 %0, %1, %2" : "=v"(lx) : "v"(l0), "v"(l1));
    asm("v_cvt_pk_bf16_f32 %0, %1, %2" : "=v"(ly) : "v"(l2), "v"(l3));
    uint2 hv, lv;
    hv.x = hx; hv.y = hy;
    lv.x = lx; lv.y = ly;
    *(uint2*)(hi_row + nb) = hv;
    *(uint2*)(lo_row + nb) = lv;
}

// B-fragment read: col n=batch=l&15 (row pointer), k=32c+8g+e — contiguous b128
__device__ __forceinline__ void read_bfrag(const u16* hi_row, const u16* lo_row, int g,
                                           bf16x8 bh[2], bf16x8 bl[2]) {
#pragma unroll
    for (int c = 0; c < 2; ++c) {
        bh[c] = *(const bf16x8*)(hi_row + 32 * c + 8 * g);
        bl[c] = *(const bf16x8*)(lo_row + 32 * c + 8 * g);
    }
}

// 8 waves, skewed pipeline (phase p: L0@t=p, L1@t=p-1, L2@t=p-2), one barrier/phase.
// R1 waves (0-3): L0 + L1 for tile i (share the B0 read; read B0,B1).
// R2 waves (4-7): L2 for tile i (read B1,B2).
// Per-CU LDS reads: 64 b128/phase (vs 80 for the {L0,L2}/{L1} split).
__global__ __launch_bounds__(512, 2)
void rnn3_fused(const float* __restrict__ x,
                const float* __restrict__ wih0, const float* __restrict__ whh0,
                const float* __restrict__ bih0, const float* __restrict__ bhh0,
                const float* __restrict__ wih1, const float* __restrict__ whh1,
                const float* __restrict__ bih1, const float* __restrict__ bhh1,
                const float* __restrict__ wih2, const float* __restrict__ whh2,
                const float* __restrict__ bih2, const float* __restrict__ bhh2,
                const float* __restrict__ w1, const float* __restrict__ bf1,
                const float* __restrict__ w2, const float* __restrict__ bf2,
                const float* __restrict__ w3, const float* __restrict__ bf3,
                float* __restrict__ out)
{
    // h state: [buf][hi/lo][layer][batch][neuron+pad], ping-pong on buf
    __shared__ __align__(16) u16 H[2][2][3][16][HST];
    __shared__ float hf[16][65];    // final h2 fp32
    __shared__ float a1s[16][33];   // head stage 1
    __shared__ float a2s[16][17];   // head stage 2

    const int tid = (int)threadIdx.x;
    const int l = tid & 63;
    const int wv = tid >> 6;        // 0..7
    const int i = wv & 3;           // neuron-tile index: neurons i*16..i*16+15
    const bool isR1 = wv < 4;
    const int ml = l & 15;
    const int g = l >> 4;           // 0..3
    const int blk = (int)blockIdx.x;
    const int nb = i * 16 + 4 * g;  // this thread's 4 neurons within its tile

    // ---- zero both H buffers (this is also the required h(-1)=0 state) ----
    {
        u32* hz = (u32*)&H[0][0][0][0][0];
        const int nz = (int)(sizeof(H) / 4);
        for (int k = tid; k < nz; k += 512) hz[k] = 0;
    }

    // ---- weight A-fragments (role-dependent, unified registers) ----
    // R1: F1=Whh0 (pairs B0), F2=Wih1 (pairs B0), F3=Whh1 (pairs B1)
    // R2: F1=Wih2 (pairs B1), F2=Whh2 (pairs B2), F3 dup (unused)
    const float* WF1 = isR1 ? whh0 : wih2;
    const float* WF2 = isR1 ? wih1 : whh2;
    const float* WF3 = whh1;
    bf16x8 F1h[2], F1l[2], F2h[2], F2l[2], F3h[2], F3l[2];
    {
        int arow = i * 16 + ml;
#pragma unroll
        for (int c = 0; c < 2; ++c) {
            int jb = 32 * c + 8 * g;
            load_wfrag(WF1, arow, jb, F1h[c], F1l[c]);
            load_wfrag(WF2, arow, jb, F2h[c], F2l[c]);
            load_wfrag(WF3, arow, jb, F3h[c], F3l[c]);
        }
    }
    float w0r[4][4], bU[4], bL[4];
#pragma unroll
    for (int r = 0; r < 4; ++r) {
        int n = nb + r;
#pragma unroll
        for (int j = 0; j < 4; ++j) w0r[r][j] = wih0[n * 4 + j];
        bU[r] = isR1 ? (bih0[n] + bhh0[n]) : (bih2[n] + bhh2[n]);
        bL[r] = bih1[n] + bhh1[n];
    }

    // B-fragment caches: R1 uses B0,B1; R2 uses B1,B2. Zero initial state.
    bf16x8 B0h[2], B0l[2], B1h[2], B1l[2], B2h[2], B2l[2];
#pragma unroll
    for (int c = 0; c < 2; ++c)
#pragma unroll
        for (int e = 0; e < 8; ++e) {
            B0h[c][e] = 0; B0l[c][e] = 0;
            B1h[c][e] = 0; B1l[c][e] = 0;
            B2h[c][e] = 0; B2l[c][e] = 0;
        }

    const float4* xv = (const float4*)x;
    const long xrow = (long)(blk * 16 + ml) * 512;   // R1 waves' batch row
    float4 xn;
    if (isR1) xn = xv[xrow];                         // x(0) prefetch

    __syncthreads();   // H zero-init visible to all

    float h2v[4] = {0.f, 0.f, 0.f, 0.f};

#pragma unroll 1
    for (int p = 0; p < 514; ++p) {
        const int cur = p & 1;

        if (isR1) {
            float4 xc = xn;
            xn = xv[xrow + ((p + 1) & 511)];         // wrap read harmless
            const bool do0 = (p < 512);
            const bool do1 = (p >= 1) && (p <= 512);

            f32x4 aU[2], aL[2];
            aU[0] = (f32x4){bU[0], bU[1], bU[2], bU[3]}; aU[1] = (f32x4){0.f, 0.f, 0.f, 0.f};
            aL[0] = (f32x4){bL[0], bL[1], bL[2], bL[3]}; aL[1] = (f32x4){0.f, 0.f, 0.f, 0.f};

            // MFMA cluster first (independent chains)
            if (do0) mm3(aU, F1h, F1l, B0h, B0l);           // Whh0 * h0(p-1)
            if (do1) { mm3(aL, F2h, F2l, B0h, B0l);         // Wih1 * h0(p-1)
                       mm3(aL, F3h, F3l, B1h, B1l); }       // Whh1 * h1(p-2)

            if (do0) {   // layer 0: + x(p) part (K=4, VALU), tanh, store h0(p)
                float hL[4];
#pragma unroll
                for (int r = 0; r < 4; ++r) {
                    float s = aU[0][r] + aU[1][r];
                    s = fmaf(xc.x, w0r[r][0], s);
                    s = fmaf(xc.y, w0r[r][1], s);
                    s = fmaf(xc.z, w0r[r][2], s);
                    s = fmaf(xc.w, w0r[r][3], s);
                    hL[r] = fast_tanh(s);
                }
                store_h(&H[cur][0][0][ml][0], &H[cur][1][0][ml][0], nb, hL);
            }
            if (do1) {   // layer 1: tanh, store h1(p-1)
                float hL[4];
#pragma unroll
                for (int r = 0; r < 4; ++r) hL[r] = fast_tanh(aL[0][r] + aL[1][r]);
                store_h(&H[cur][0][1][ml][0], &H[cur][1][1][ml][0], nb, hL);
            }
        } else {
            const bool do2 = (p >= 2);
            f32x4 aV[2];
            aV[0] = (f32x4){bU[0], bU[1], bU[2], bU[3]}; aV[1] = (f32x4){0.f, 0.f, 0.f, 0.f};
            if (do2) {   // layer 2: Wih2*h1(p-2) + Whh2*h2(p-3), tanh, store h2(p-2)
                mm3(aV, F1h, F1l, B1h, B1l);
                mm3(aV, F2h, F2l, B2h, B2l);
                float hL[4];
#pragma unroll
                for (int r = 0; r < 4; ++r) { hL[r] = fast_tanh(aV[0][r] + aV[1][r]); h2v[r] = hL[r]; }
                store_h(&H[cur][0][2][ml][0], &H[cur][1][2][ml][0], nb, hL);
            }
        }

        __syncthreads();

        if (isR1) {
            read_bfrag(&H[cur][0][0][ml][0], &H[cur][1][0][ml][0], g, B0h, B0l);  // h0
            read_bfrag(&H[cur][0][1][ml][0], &H[cur][1][1][ml][0], g, B1h, B1l);  // h1
        } else {
            read_bfrag(&H[cur][0][1][ml][0], &H[cur][1][1][ml][0], g, B1h, B1l);  // h1
            read_bfrag(&H[cur][0][2][ml][0], &H[cur][1][2][ml][0], g, B2h, B2l);  // h2
        }
    }

    // ---------- MLP head (fp32, one-time) ----------
    if (!isR1) {   // R2 waves hold h2(511)
#pragma unroll
        for (int r = 0; r < 4; ++r) hf[ml][nb + r] = h2v[r];
    }
    __syncthreads();

    {   // stage 1: [16x64] @ w1^T -> relu -> [16x32]; 512 threads, 1 output each
        int r = tid & 15, o = tid >> 4;   // o 0..31
        float s = bf1[o];
        for (int j = 0; j < 64; ++j) s = fmaf(hf[r][j], w1[o * 64 + j], s);
        a1s[r][o] = fmaxf(s, 0.f);
    }
    __syncthreads();
    if (tid < 256) {   // stage 2: [16x32] @ w2^T -> [16x16]; one output each
        int r = tid & 15, o = tid >> 4;
        float s = bf2[o];
        for (int j = 0; j < 32; ++j) s = fmaf(a1s[r][j], w2[o * 32 + j], s);
        a2s[r][o] = s;
    }
    __syncthreads();
    if (tid < 16) {   // stage 3: [16x16] @ w3^T -> [16]
        float s = bf3[0];
        for (int j = 0; j < 16; ++j) s = fmaf(a2s[tid][j], w3[j], s);
        out[blk * 16 + tid] = s;
    }
}

extern "C" void kernel_launch(void* const* d_in, const int* in_sizes, int n_in,
                              void* d_out, int out_size, void* d_ws, size_t ws_size,
                              hipStream_t stream) {
    const float* x    = (const float*)d_in[0];
    const float* wih0 = (const float*)d_in[1];
    const float* whh0 = (const float*)d_in[2];
    const float* bih0 = (const float*)d_in[3];
    const float* bhh0 = (const float*)d_in[4];
    const float* wih1 = (const float*)d_in[5];
    const float* whh1 = (const float*)d_in[6];
    const float* bih1 = (const float*)d_in[7];
    const float* bhh1 = (const float*)d_in[8];
    const float* wih2 = (const float*)d_in[9];
    const float* whh2 = (const float*)d_in[10];
    const float* bih2 = (const float*)d_in[11];
    const float* bhh2 = (const float*)d_in[12];
    const float* w1   = (const float*)d_in[13];
    const float* bf1  = (const float*)d_in[14];
    const float* w2   = (const float*)d_in[15];
    const float* bf2  = (const float*)d_in[16];
    const float* w3   = (const float*)d_in[17];
    const float* bf3  = (const float*)d_in[18];

    rnn3_fused<<<dim3(256), dim3(512), 0, stream>>>(
        x, wih0, whh0, bih0, bhh0, wih1, whh1, bih1, bhh1,
        wih2, whh2, bih2, bhh2, w1, bf1, w2, bf2, w3, bf3,
        (float*)d_out);
}